// Round 1
// baseline (221.365 us; speedup 1.0000x reference)
//
#include <hip/hip_runtime.h>
#include <math.h>

// GSchNet continuous-filter convolution edge embedding.
// Key insight: out[e,:] = f(dist(e)) where f: R -> R^128 is the RBF+MLP,
// a smooth function of ONE scalar. Tabulate f on [0,16] (4096 steps) and
// linearly interpolate per edge. Interp error ~ |f''| h^2/8 ~ 1e-5 << 1.5e-2.

#define N_NODES_C   50000
#define N_EDGES_C   800000
#define LATENT_C    128
#define N_CENTERS_C 100
#define TABK        4096
#define DMAX        16.0f        // all RBFs ~exp(-36)=2e-16 beyond this; f == 0 (b2=0 handled generally)
#define LN2F        0.69314718056f

__device__ __forceinline__ float shifted_softplus(float x) {
    // softplus(x) - ln2, numerically stable
    return fmaxf(x, 0.0f) + log1pf(expf(-fabsf(x))) - LN2F;
}

// One block (128 threads) per table row k: d = k * (DMAX/TABK).
__global__ void build_table_kernel(const float* __restrict__ W1, const float* __restrict__ b1,
                                   const float* __restrict__ W2, const float* __restrict__ b2,
                                   float* __restrict__ table) {
    __shared__ float rbf[N_CENTERS_C];
    __shared__ float hbuf[LATENT_C];
    const int j = threadIdx.x;          // 0..127
    const float d = (float)blockIdx.x * (DMAX / (float)TABK);

    if (j < N_CENTERS_C) {
        const float c = (float)j * (10.0f / 99.0f);   // linspace(0,10,100)
        const float x = d - c;
        rbf[j] = expf(-x * x);
    }
    __syncthreads();

    // layer 1: a_j = b1[j] + sum_c rbf[c] * W1[c][j]   (W1 row-major [100][128])
    float a = b1[j];
    #pragma unroll 4
    for (int c = 0; c < N_CENTERS_C; ++c)
        a = fmaf(rbf[c], W1[c * LATENT_C + j], a);
    hbuf[j] = shifted_softplus(a);
    __syncthreads();

    // layer 2: out_j = b2[j] + sum_i h[i] * W2[i][j]   (W2 row-major [128][128])
    float o = b2[j];
    #pragma unroll 4
    for (int i = 0; i < LATENT_C; ++i)
        o = fmaf(hbuf[i], W2[i * LATENT_C + j], o);

    table[(size_t)blockIdx.x * LATENT_C + j] = o;
}

// Wave-per-edge: 64 lanes x float2 = 128 outputs. Grid-stride over edges.
__global__ void edge_interp_kernel(const float* __restrict__ nodes,
                                   const int* __restrict__ senders,
                                   const int* __restrict__ receivers,
                                   const float* __restrict__ table,
                                   float* __restrict__ out) {
    const int lane = threadIdx.x & 63;
    const int wid  = (blockIdx.x * blockDim.x + threadIdx.x) >> 6;
    const int nw   = (gridDim.x * blockDim.x) >> 6;

    for (int e = wid; e < N_EDGES_C; e += nw) {
        const int s = senders[e];
        const int r = receivers[e];
        const float dx = nodes[3 * s + 0] - nodes[3 * r + 0];
        const float dy = nodes[3 * s + 1] - nodes[3 * r + 1];
        const float dz = nodes[3 * s + 2] - nodes[3 * r + 2];
        const float dist = sqrtf(fmaf(dx, dx, fmaf(dy, dy, dz * dz)));

        // table coordinate, clamped so k+1 stays in [0, TABK]
        float t = fminf(dist * ((float)TABK / DMAX), (float)TABK - 0.5f);
        const int   k = (int)t;
        const float f = t - (float)k;

        const float2* r0 = (const float2*)(table + (size_t)k * LATENT_C);
        const float2* r1 = (const float2*)(table + (size_t)(k + 1) * LATENT_C);
        const float2 a = r0[lane];
        const float2 b = r1[lane];
        float2 o;
        o.x = fmaf(f, b.x - a.x, a.x);
        o.y = fmaf(f, b.y - a.y, a.y);
        ((float2*)(out + (size_t)e * LATENT_C))[lane] = o;
    }
}

// Fallback if workspace is too small for the table: direct per-edge MLP.
__global__ void edge_direct_kernel(const float* __restrict__ nodes,
                                   const int* __restrict__ senders,
                                   const int* __restrict__ receivers,
                                   const float* __restrict__ W1, const float* __restrict__ b1,
                                   const float* __restrict__ W2, const float* __restrict__ b2,
                                   float* __restrict__ out) {
    __shared__ float rbf[N_CENTERS_C];
    __shared__ float hbuf[LATENT_C];
    const int j = threadIdx.x;

    for (int e = blockIdx.x; e < N_EDGES_C; e += gridDim.x) {
        const int s = senders[e];
        const int r = receivers[e];
        const float dx = nodes[3 * s + 0] - nodes[3 * r + 0];
        const float dy = nodes[3 * s + 1] - nodes[3 * r + 1];
        const float dz = nodes[3 * s + 2] - nodes[3 * r + 2];
        const float dist = sqrtf(fmaf(dx, dx, fmaf(dy, dy, dz * dz)));

        if (j < N_CENTERS_C) {
            const float c = (float)j * (10.0f / 99.0f);
            const float x = dist - c;
            rbf[j] = expf(-x * x);
        }
        __syncthreads();

        float a = b1[j];
        #pragma unroll 4
        for (int c = 0; c < N_CENTERS_C; ++c)
            a = fmaf(rbf[c], W1[c * LATENT_C + j], a);
        hbuf[j] = shifted_softplus(a);
        __syncthreads();

        float o = b2[j];
        #pragma unroll 4
        for (int i = 0; i < LATENT_C; ++i)
            o = fmaf(hbuf[i], W2[i * LATENT_C + j], o);
        out[(size_t)e * LATENT_C + j] = o;

        __syncthreads();   // protect rbf/hbuf before next grid-stride iteration
    }
}

extern "C" void kernel_launch(void* const* d_in, const int* in_sizes, int n_in,
                              void* d_out, int out_size, void* d_ws, size_t ws_size,
                              hipStream_t stream) {
    const float* nodes     = (const float*)d_in[0];
    const int*   senders   = (const int*)  d_in[1];
    const int*   receivers = (const int*)  d_in[2];
    const float* W1        = (const float*)d_in[3];
    const float* b1        = (const float*)d_in[4];
    const float* W2        = (const float*)d_in[5];
    const float* b2        = (const float*)d_in[6];
    float*       out       = (float*)d_out;

    const size_t table_bytes = (size_t)(TABK + 1) * LATENT_C * sizeof(float);

    if (ws_size >= table_bytes) {
        float* table = (float*)d_ws;
        // Build f(d) table: TABK+1 rows (row TABK needed for interp at the clamp).
        build_table_kernel<<<TABK + 1, LATENT_C, 0, stream>>>(W1, b1, W2, b2, table);
        // Interpolate per edge: 2048 blocks x 256 thr = 8192 waves, ~98 edges/wave.
        edge_interp_kernel<<<2048, 256, 0, stream>>>(nodes, senders, receivers, table, out);
    } else {
        edge_direct_kernel<<<16384, LATENT_C, 0, stream>>>(nodes, senders, receivers,
                                                           W1, b1, W2, b2, out);
    }
}

// Round 2
// 115.346 us; speedup vs baseline: 1.9191x; 1.9191x over previous
//
#include <hip/hip_runtime.h>
#include <math.h>

// GSchNet continuous-filter convolution edge embedding.
// out[e,:] = f(dist(e)) where f: R -> R^128 (RBF+MLP) is a smooth function of
// ONE scalar. Tabulate f on [0,16] at 4096 steps, lerp per edge.
// Round 1 passed at 221us (floor ~60us). This round: 3-phase pipeline
//   A) build table (4097x128 f32, 2.1 MB in ws)
//   B) compute per-edge table coordinate t[e] (3.2 MB in ws)
//   C) half-wave-per-edge float4 lerp + NON-TEMPORAL stores (keep L2 for table)

#define N_NODES_C   50000
#define N_EDGES_C   800000
#define LATENT_C    128
#define N_CENTERS_C 100
#define TABK        4096
#define DMAX        16.0f
#define LN2F        0.69314718056f

typedef float v4f __attribute__((ext_vector_type(4)));

__device__ __forceinline__ float shifted_softplus(float x) {
    return fmaxf(x, 0.0f) + log1pf(expf(-fabsf(x))) - LN2F;
}

// -------- Phase A: one block (128 threads) per table row k, d = k*(DMAX/TABK)
__global__ void build_table_kernel(const float* __restrict__ W1, const float* __restrict__ b1,
                                   const float* __restrict__ W2, const float* __restrict__ b2,
                                   float* __restrict__ table) {
    __shared__ float rbf[N_CENTERS_C];
    __shared__ float hbuf[LATENT_C];
    const int j = threadIdx.x;
    const float d = (float)blockIdx.x * (DMAX / (float)TABK);

    if (j < N_CENTERS_C) {
        const float c = (float)j * (10.0f / 99.0f);   // linspace(0,10,100)
        const float x = d - c;
        rbf[j] = expf(-x * x);
    }
    __syncthreads();

    float a = b1[j];
    #pragma unroll 4
    for (int c = 0; c < N_CENTERS_C; ++c)
        a = fmaf(rbf[c], W1[c * LATENT_C + j], a);
    hbuf[j] = shifted_softplus(a);
    __syncthreads();

    float o = b2[j];
    #pragma unroll 4
    for (int i = 0; i < LATENT_C; ++i)
        o = fmaf(hbuf[i], W2[i * LATENT_C + j], o);

    table[(size_t)blockIdx.x * LATENT_C + j] = o;
}

// -------- Phase B: thread-per-edge table coordinate
__global__ void compute_t_kernel(const float* __restrict__ nodes,
                                 const int* __restrict__ senders,
                                 const int* __restrict__ receivers,
                                 float* __restrict__ tcoord) {
    const int e = blockIdx.x * blockDim.x + threadIdx.x;
    if (e >= N_EDGES_C) return;
    const int s = senders[e];
    const int r = receivers[e];
    const float dx = nodes[3 * s + 0] - nodes[3 * r + 0];
    const float dy = nodes[3 * s + 1] - nodes[3 * r + 1];
    const float dz = nodes[3 * s + 2] - nodes[3 * r + 2];
    const float dist = sqrtf(fmaf(dx, dx, fmaf(dy, dy, dz * dz)));
    // clamp so k+1 <= TABK stays in table
    tcoord[e] = fminf(dist * ((float)TABK / DMAX), (float)TABK - 0.5f);
}

// -------- Phase C: half-wave (32 lanes x float4) per edge; 2 slots = 4 edges/iter.
// Non-temporal stores keep table + tcoord L2-resident.
__global__ void edge_write_kernel(const float* __restrict__ tcoord,
                                  const float* __restrict__ table,
                                  float* __restrict__ out) {
    const int lane = threadIdx.x & 63;
    const int half = lane >> 5;          // edge within a slot
    const int li   = lane & 31;          // float4 index within the 128-f row
    const int wid  = (blockIdx.x * blockDim.x + threadIdx.x) >> 6;
    const int nw   = (gridDim.x * blockDim.x) >> 6;

    for (int base = wid * 4; base + 3 < N_EDGES_C; base += nw * 4) {
        // slot 0: edges base, base+1 ; slot 1: edges base+2, base+3
        const float t0 = tcoord[base + half];
        const float t1 = tcoord[base + 2 + half];
        const int   k0 = (int)t0;  const float f0 = t0 - (float)k0;
        const int   k1 = (int)t1;  const float f1 = t1 - (float)k1;

        const v4f* r0 = (const v4f*)(table + (size_t)k0 * LATENT_C);
        const v4f* r1 = (const v4f*)(table + (size_t)k1 * LATENT_C);
        const v4f a0 = r0[li], b0 = r0[li + 32];   // +32 v4f = next row (k0+1)
        const v4f a1 = r1[li], b1 = r1[li + 32];

        v4f o0, o1;
        #pragma unroll
        for (int c = 0; c < 4; ++c) {
            o0[c] = fmaf(f0, b0[c] - a0[c], a0[c]);
            o1[c] = fmaf(f1, b1[c] - a1[c], a1[c]);
        }

        v4f* po0 = (v4f*)(out + (size_t)base * LATENT_C);        // covers edges base,base+1
        v4f* po1 = (v4f*)(out + (size_t)(base + 2) * LATENT_C);  // covers edges base+2,base+3
        __builtin_nontemporal_store(o0, &po0[lane]);
        __builtin_nontemporal_store(o1, &po1[lane]);
    }
}

// -------- Fallback (ws too small): direct per-edge MLP
__global__ void edge_direct_kernel(const float* __restrict__ nodes,
                                   const int* __restrict__ senders,
                                   const int* __restrict__ receivers,
                                   const float* __restrict__ W1, const float* __restrict__ b1,
                                   const float* __restrict__ W2, const float* __restrict__ b2,
                                   float* __restrict__ out) {
    __shared__ float rbf[N_CENTERS_C];
    __shared__ float hbuf[LATENT_C];
    const int j = threadIdx.x;

    for (int e = blockIdx.x; e < N_EDGES_C; e += gridDim.x) {
        const int s = senders[e];
        const int r = receivers[e];
        const float dx = nodes[3 * s + 0] - nodes[3 * r + 0];
        const float dy = nodes[3 * s + 1] - nodes[3 * r + 1];
        const float dz = nodes[3 * s + 2] - nodes[3 * r + 2];
        const float dist = sqrtf(fmaf(dx, dx, fmaf(dy, dy, dz * dz)));

        if (j < N_CENTERS_C) {
            const float c = (float)j * (10.0f / 99.0f);
            const float x = dist - c;
            rbf[j] = expf(-x * x);
        }
        __syncthreads();

        float a = b1[j];
        #pragma unroll 4
        for (int c = 0; c < N_CENTERS_C; ++c)
            a = fmaf(rbf[c], W1[c * LATENT_C + j], a);
        hbuf[j] = shifted_softplus(a);
        __syncthreads();

        float o = b2[j];
        #pragma unroll 4
        for (int i = 0; i < LATENT_C; ++i)
            o = fmaf(hbuf[i], W2[i * LATENT_C + j], o);
        out[(size_t)e * LATENT_C + j] = o;

        __syncthreads();
    }
}

extern "C" void kernel_launch(void* const* d_in, const int* in_sizes, int n_in,
                              void* d_out, int out_size, void* d_ws, size_t ws_size,
                              hipStream_t stream) {
    const float* nodes     = (const float*)d_in[0];
    const int*   senders   = (const int*)  d_in[1];
    const int*   receivers = (const int*)  d_in[2];
    const float* W1        = (const float*)d_in[3];
    const float* b1        = (const float*)d_in[4];
    const float* W2        = (const float*)d_in[5];
    const float* b2        = (const float*)d_in[6];
    float*       out       = (float*)d_out;

    const size_t table_bytes = (size_t)(TABK + 1) * LATENT_C * sizeof(float); // 2,097,664
    const size_t t_bytes     = (size_t)N_EDGES_C * sizeof(float);             // 3,200,000

    if (ws_size >= table_bytes + t_bytes) {
        float* table  = (float*)d_ws;
        float* tcoord = (float*)((char*)d_ws + table_bytes);

        build_table_kernel<<<TABK + 1, LATENT_C, 0, stream>>>(W1, b1, W2, b2, table);
        compute_t_kernel<<<(N_EDGES_C + 255) / 256, 256, 0, stream>>>(nodes, senders,
                                                                      receivers, tcoord);
        // 2048 blocks x 4 waves = 8192 waves = exactly the 256CU x 32wave residency cap
        edge_write_kernel<<<2048, 256, 0, stream>>>(tcoord, table, out);
    } else {
        edge_direct_kernel<<<16384, LATENT_C, 0, stream>>>(nodes, senders, receivers,
                                                           W1, b1, W2, b2, out);
    }
}